// Round 14
// baseline (116.079 us; speedup 1.0000x reference)
//
#include <hip/hip_runtime.h>

// Problem constants (match reference)
#define NB 32768   // batch rows
#define NF 256     // features
#define NH 8       // hidden dim
#define FPB 64     // features per block (24 KB params -> L1-resident)
#define RPB 64     // rows per block
#define NRG 4      // rowgroups (= waves) per block
#define RPG (RPB / NRG)   // 16 rows per thread
#define RT 4       // row tile (rows-inner loop)
#define NT (RPG / RT)     // 4 tiles per thread

// Round 12 proved the allocator will NEVER keep 96 param floats resident
// (VGPR=60 even with asm pins; ~2x instruction count from the refill
// stream). This kernel restructures so param residency isn't needed:
// rows-inner tiles of RT=4 with the h-loop OUTER — each W2 row (2 x b128,
// transient) feeds 32 FMAs across 4 rows then dies. Live state ~60-90 regs.
// Param re-reads happen once per 4 rows from a 24 KB per-block working set
// (64 features) that fits L1; fb = bid&3 pins one fb per XCD (round-robin)
// so per-XCD L2 stays warm. No LDS; grid 2048 -> 8 blocks/CU available.
// Row sums: 64-lane butterfly per wave + 4-way atomicAdd (out_sum memset).

typedef float f4 __attribute__((ext_vector_type(4)));

__global__ __launch_bounds__(256, 4) void NAM_49314814493074_kernel(
    const float* __restrict__ input,   // [B, F]
    const float* __restrict__ W1,      // [F, 8]
    const float* __restrict__ b1,      // [F, 8]
    const float* __restrict__ W2,      // [F, 8, 8]
    const float* __restrict__ b2,      // [F, 8]
    const float* __restrict__ W3,      // [F, 8]
    float* __restrict__ out_sum,       // [B]   (pre-zeroed)
    float* __restrict__ out_w)         // [B, F]
{
    const int t    = threadIdx.x;
    const int lane = t & 63;           // feature within block
    const int rg   = t >> 6;           // rowgroup (wave) 0..3
    const int fb   = blockIdx.x & 3;   // feature-block: one per XCD pair
    const int rb   = blockIdx.x >> 2;  // row-block 0..511
    const int f    = fb * FPB + lane;  // global feature
    const int row0 = rb * RPB + rg * RPG;

    const float* xin  = input + (size_t)row0 * NF + f;
    float*       wout = out_w + (size_t)row0 * NF + f;

    const f4* pW1 = reinterpret_cast<const f4*>(W1 + (size_t)f * NH);
    const f4* pB1 = reinterpret_cast<const f4*>(b1 + (size_t)f * NH);
    const f4* pB2 = reinterpret_cast<const f4*>(b2 + (size_t)f * NH);
    const f4* pW3 = reinterpret_cast<const f4*>(W3 + (size_t)f * NH);
    const f4* pW2 = reinterpret_cast<const f4*>(W2 + (size_t)f * NH * NH);

    #pragma unroll 1                   // keep body ~3.5 KB, I$-warm
    for (int tile = 0; tile < NT; ++tile) {
        const int rbase = tile * RT;

        // x for this tile (coalesced 256B wave-loads)
        float xv[RT];
        #pragma unroll
        for (int r = 0; r < RT; ++r)
            xv[r] = xin[(size_t)(rbase + r) * NF];

        // layer-1 params for this tile (L1-hot after sweep 1)
        f4 w1a = pW1[0], w1b = pW1[1];
        f4 b1a = pB1[0], b1b = pB1[1];

        float acc[RT][NH];

        // h = 0 peel: init acc (b2 folded in at the end instead)
        {
            f4 wa = pW2[0], wb = pW2[1];
            #pragma unroll
            for (int r = 0; r < RT; ++r) {
                const float h1 = fmaxf(fmaf(xv[r], w1a[0], b1a[0]), 0.0f);
                #pragma unroll
                for (int k = 0; k < 4; ++k) {
                    acc[r][k]     = h1 * wa[k];
                    acc[r][4 + k] = h1 * wb[k];
                }
            }
        }
        // h = 1..7: stream one W2 row at a time, apply to all 4 rows
        #pragma unroll
        for (int h = 1; h < NH; ++h) {
            const f4 wa = pW2[2 * h], wb = pW2[2 * h + 1];
            const float w1h = (h < 4) ? w1a[h] : w1b[h - 4];
            const float b1h = (h < 4) ? b1a[h] : b1b[h - 4];
            #pragma unroll
            for (int r = 0; r < RT; ++r) {
                const float h1 = fmaxf(fmaf(xv[r], w1h, b1h), 0.0f);
                #pragma unroll
                for (int k = 0; k < 4; ++k) {
                    acc[r][k]     = fmaf(h1, wa[k], acc[r][k]);
                    acc[r][4 + k] = fmaf(h1, wb[k], acc[r][4 + k]);
                }
            }
        }

        // output layer + store + wave-wide row sum
        const f4 b2a = pB2[0], b2b = pB2[1];
        const f4 w3a = pW3[0], w3b = pW3[1];
        #pragma unroll
        for (int r = 0; r < RT; ++r) {
            float s = 0.0f;
            #pragma unroll
            for (int k = 0; k < 4; ++k) {
                s = fmaf(fmaxf(acc[r][k]     + b2a[k], 0.0f), w3a[k], s);
                s = fmaf(fmaxf(acc[r][4 + k] + b2b[k], 0.0f), w3b[k], s);
            }
            wout[(size_t)(rbase + r) * NF] = s;

            float v = s;
            #pragma unroll
            for (int off = 32; off > 0; off >>= 1)
                v += __shfl_xor(v, off, 64);
            if (lane == 0)
                atomicAdd(&out_sum[row0 + rbase + r], v);
        }
    }
}

extern "C" void kernel_launch(void* const* d_in, const int* in_sizes, int n_in,
                              void* d_out, int out_size, void* d_ws, size_t ws_size,
                              hipStream_t stream) {
    const float* input = (const float*)d_in[0];
    const float* W1    = (const float*)d_in[1];
    const float* b1    = (const float*)d_in[2];
    const float* W2    = (const float*)d_in[3];
    const float* b2    = (const float*)d_in[4];
    const float* W3    = (const float*)d_in[5];

    float* out = (float*)d_out;          // [B] sums, then [B,F] w
    float* out_sum = out;
    float* out_w   = out + NB;

    // zero the atomic-accumulated region (harness poisons d_out with 0xAA)
    hipMemsetAsync(out_sum, 0, NB * sizeof(float), stream);

    dim3 grid((NF / FPB) * (NB / RPB));  // 4 x 512 = 2048 blocks
    dim3 block(256);                     // 4 waves: 64 features x 4 rowgroups
    NAM_49314814493074_kernel<<<grid, block, 0, stream>>>(
        input, W1, b1, W2, b2, W3, out_sum, out_w);
}